// Round 2
// baseline (761.964 us; speedup 1.0000x reference)
//
#include <hip/hip_runtime.h>

typedef unsigned short ushort_t;
typedef short s8v __attribute__((ext_vector_type(8)));
typedef unsigned short ushort8 __attribute__((ext_vector_type(8)));
typedef float floatx4 __attribute__((ext_vector_type(4)));

#define MFMA16(a, b, c) __builtin_amdgcn_mfma_f32_16x16x32_bf16((a), (b), (c), 0, 0, 0)

static constexpr int B_SZ = 8;
static constexpr int L = 8192;
static constexpr int H = 1024;
static constexpr int M_TOT = B_SZ * L;   // 65536 rows
static constexpr int S_CH = 32;          // scan chunk length
static constexpr int NC = L / S_CH;      // 256 chunks per batch
static constexpr int NCHUNK = B_SZ * NC; // 2048 chunks total

// round-to-nearest-even fp32 -> bf16 bits
__device__ inline ushort_t f2bf(float f) {
    union { float f; unsigned u; } v; v.f = f;
    unsigned r = v.u + 0x7fffu + ((v.u >> 16) & 1u);
    return (ushort_t)(r >> 16);
}
__device__ inline unsigned pack_bf(float re, float im) {
    return (unsigned)f2bf(re) | ((unsigned)f2bf(im) << 16);
}

// ---------------------------------------------------------------- params ----
// params2[p]      = (dA_r, dA_i)
// params2[64+p]   = (s_r, s_i)        s = dt/den
// params2[128+p]  = dA^S_CH
__global__ void params_kernel(const float* __restrict__ A_real,
                              const float* __restrict__ A_imag,
                              const float* __restrict__ inv_dt,
                              float2* __restrict__ params2) {
    int p = threadIdx.x;  // 64 threads
    float x = inv_dt[p];
    float dt = (x > 20.f) ? x : log1pf(expf(x));
    float ar = A_real[p], ai = A_imag[p];
    float dr = 1.f - 0.5f * dt * ar;
    float di = -0.5f * dt * ai;
    float inv = 1.f / fmaf(dr, dr, di * di);
    float nr = 1.f + 0.5f * dt * ar, ni = 0.5f * dt * ai;
    float dAr = (nr * dr + ni * di) * inv;
    float dAi = (ni * dr - nr * di) * inv;
    params2[p] = make_float2(dAr, dAi);
    params2[64 + p] = make_float2(dt * dr * inv, -dt * di * inv);
    float pr = dAr, pi = dAi;
    for (int k = 1; k < S_CH; k++) {
        float tr = pr * dAr - pi * dAi;
        float ti = pr * dAi + pi * dAr;
        pr = tr; pi = ti;
    }
    params2[128 + p] = make_float2(pr, pi);
}

// -------------------------------------------------- build bf16 weights ----
// Interleaved complex columns: n = 2p -> Re plane, n = 2p+1 -> Im plane.
// W1T[n][k] : n even: Re(s_p * B_p[k]); odd: Im(s_p * B_p[k])   (k<1024)
// CeffT[h][k]: k even: 2*C_r[h][k/2];   odd: -2*C_i[h][k/2]     (k<128)
__global__ void build_w(const float* __restrict__ Br, const float* __restrict__ Bi,
                        const float* __restrict__ Cr, const float* __restrict__ Ci,
                        const float2* __restrict__ params2,
                        ushort_t* __restrict__ W1T, ushort_t* __restrict__ CeffT) {
    int t = blockIdx.x * 256 + threadIdx.x;
    if (t < 128 * 1024) {
        int n = t >> 10, k = t & 1023;
        int p = n >> 1;
        float2 s = params2[64 + p];
        float br = Br[p * 1024 + k], bi = Bi[p * 1024 + k];
        float v = (n & 1) ? (s.x * bi + s.y * br) : (s.x * br - s.y * bi);
        W1T[t] = f2bf(v);
    } else {
        int t2 = t - 128 * 1024;
        int h = t2 >> 7, k = t2 & 127;
        int p = k >> 1;
        float v = (k & 1) ? -2.f * Ci[h * 64 + p] : 2.f * Cr[h * 64 + p];
        CeffT[t2] = f2bf(v);
    }
}

// ------------------------------------------------------------- GEMM 1 ----
// Bu[M_TOT][128] = u[M_TOT][1024] @ W;  W[k][n] = W1T[n][k].
// 128-row tile per block, BK=64, register prefetch of next tile.
__global__ __launch_bounds__(256) void gemm1(const float* __restrict__ u,
                                             const ushort_t* __restrict__ W1T,
                                             float* __restrict__ Bu) {
    __shared__ ushort_t As[128][72];  // stride 144B -> conflict-free-ish
    __shared__ ushort_t Bs[128][72];
    int tid = threadIdx.x;
    int wave = tid >> 6, lane = tid & 63;
    int q = lane >> 4, mn = lane & 15;
    size_t row0 = (size_t)blockIdx.x * 128;
    int r = tid >> 1, half = tid & 1;

    const float* up_base = u + (row0 + r) * 1024 + half * 32;
    const ushort_t* wp_base = W1T + r * 1024 + half * 32;

    float4 fu[8];
    ushort8 wb[4];
    #pragma unroll
    for (int i = 0; i < 8; i++) fu[i] = ((const float4*)up_base)[i];
    #pragma unroll
    for (int i = 0; i < 4; i++) wb[i] = ((const ushort8*)wp_base)[i];

    floatx4 acc[2][8] = {};

    for (int t = 0; t < 16; t++) {
        __syncthreads();
        #pragma unroll
        for (int i = 0; i < 4; i++) {
            float4 a = fu[2 * i], b = fu[2 * i + 1];
            ushort8 v;
            v[0] = f2bf(a.x); v[1] = f2bf(a.y); v[2] = f2bf(a.z); v[3] = f2bf(a.w);
            v[4] = f2bf(b.x); v[5] = f2bf(b.y); v[6] = f2bf(b.z); v[7] = f2bf(b.w);
            *(ushort8*)&As[r][half * 32 + i * 8] = v;
            *(ushort8*)&Bs[r][half * 32 + i * 8] = wb[i];
        }
        __syncthreads();
        if (t < 15) {
            const float4* upn = (const float4*)(up_base + (t + 1) * 64);
            #pragma unroll
            for (int i = 0; i < 8; i++) fu[i] = upn[i];
            const ushort8* wpn = (const ushort8*)(wp_base + (t + 1) * 64);
            #pragma unroll
            for (int i = 0; i < 4; i++) wb[i] = wpn[i];
        }
        #pragma unroll
        for (int kk = 0; kk < 64; kk += 32) {
            s8v a0 = *(const s8v*)&As[wave * 32 + mn][kk + q * 8];
            s8v a1 = *(const s8v*)&As[wave * 32 + 16 + mn][kk + q * 8];
            #pragma unroll
            for (int j = 0; j < 8; j++) {
                s8v bf = *(const s8v*)&Bs[j * 16 + mn][kk + q * 8];
                acc[0][j] = MFMA16(a0, bf, acc[0][j]);
                acc[1][j] = MFMA16(a1, bf, acc[1][j]);
            }
        }
    }
    #pragma unroll
    for (int i = 0; i < 2; i++)
        #pragma unroll
        for (int j = 0; j < 8; j++)
            #pragma unroll
            for (int reg = 0; reg < 4; reg++) {
                size_t row = row0 + wave * 32 + i * 16 + q * 4 + reg;
                Bu[row * 128 + j * 16 + mn] = acc[i][j][reg];
            }
}

// --------------------------------------------------------- scan pass A ----
// Per-chunk local scan (zero initial state), records end state only.
// chunk = b*NC + c; Bu2 is float2 (re,im) per p.
__global__ void scan_ends(const float2* __restrict__ Bu2,
                          const float2* __restrict__ params2,
                          float2* __restrict__ end2) {
    int tid = threadIdx.x;
    int p = tid & 63;
    int chunk = blockIdx.x * 4 + (tid >> 6);
    float2 dA = params2[p];
    const float2* src = Bu2 + (size_t)chunk * (S_CH * 64) + p;
    float hr = 0.f, hi = 0.f;
    #pragma unroll
    for (int l = 0; l < S_CH; l++) {
        float2 v = src[(size_t)l * 64];
        float nr = fmaf(dA.x, hr, fmaf(-dA.y, hi, v.x));
        float ni = fmaf(dA.x, hi, fmaf(dA.y, hr, v.y));
        hr = nr; hi = ni;
    }
    end2[(size_t)chunk * 64 + p] = make_float2(hr, hi);
}

// --------------------------------------------------------- carry scan ----
// carry[c] = true state entering chunk c (carry[0] = h0).
__global__ void scan_carry(const float2* __restrict__ end2,
                           const float2* __restrict__ params2,
                           const float* __restrict__ h0r, const float* __restrict__ h0i,
                           float2* __restrict__ carry2) {
    int b = blockIdx.x, p = threadIdx.x;
    float2 aS = params2[128 + p];
    float cr = h0r[b * 64 + p], ci = h0i[b * 64 + p];
    const float2* e = end2 + (size_t)b * NC * 64 + p;
    float2* cw = carry2 + (size_t)b * NC * 64 + p;
    for (int c = 0; c < NC; c++) {
        cw[(size_t)c * 64] = make_float2(cr, ci);
        float2 ev = e[(size_t)c * 64];
        float nr = fmaf(aS.x, cr, fmaf(-aS.y, ci, ev.x));
        float ni = fmaf(aS.x, ci, fmaf(aS.y, cr, ev.y));
        cr = nr; ci = ni;
    }
}

// --------------------------------------------------------- scan pass B ----
// Full scan from carry, writes packed bf16 (re,im) words + h_last.
__global__ void scan_final(const float2* __restrict__ Bu2,
                           const float2* __restrict__ params2,
                           const float2* __restrict__ carry2,
                           unsigned* __restrict__ hfix_u,
                           float* __restrict__ out_hlast) {
    int tid = threadIdx.x;
    int p = tid & 63;
    int chunk = blockIdx.x * 4 + (tid >> 6);
    float2 dA = params2[p];
    float2 cv = carry2[(size_t)chunk * 64 + p];
    float hr = cv.x, hi = cv.y;
    const float2* src = Bu2 + (size_t)chunk * (S_CH * 64) + p;
    unsigned* dst = hfix_u + (size_t)chunk * (S_CH * 64) + p;
    #pragma unroll
    for (int l = 0; l < S_CH; l++) {
        float2 v = src[(size_t)l * 64];
        float nr = fmaf(dA.x, hr, fmaf(-dA.y, hi, v.x));
        float ni = fmaf(dA.x, hi, fmaf(dA.y, hr, v.y));
        hr = nr; hi = ni;
        dst[(size_t)l * 64] = pack_bf(hr, hi);
    }
    if ((chunk & (NC - 1)) == NC - 1) {
        int b = chunk >> 8;
        out_hlast[b * 64 + p] = hr;
        out_hlast[512 + b * 64 + p] = hi;
    }
}

// ------------------------------------------------------------- GEMM 2 ----
// y[row][h] = sum_k hfix[row][k]*CeffT[h][k] + D[h]*u[row][h]
// As staged once; Bs register-prefetched across 8 column tiles.
__global__ __launch_bounds__(256) void gemm2(const ushort_t* __restrict__ hfix,
                                             const ushort_t* __restrict__ CeffT,
                                             const float* __restrict__ u,
                                             const float* __restrict__ Dv,
                                             float* __restrict__ y) {
    __shared__ ushort_t As[128][136];  // stride 272B
    __shared__ ushort_t Bs[128][136];
    int tid = threadIdx.x;
    int wave = tid >> 6, lane = tid & 63;
    int q = lane >> 4, mn = lane & 15;
    size_t row0 = (size_t)blockIdx.x * 128;
    int r = tid >> 1, half = tid & 1;

    {
        const ushort8* src = (const ushort8*)(hfix + (row0 + r) * 128 + half * 64);
        #pragma unroll
        for (int i = 0; i < 8; i++) *(ushort8*)&As[r][half * 64 + i * 8] = src[i];
    }
    const ushort_t* bbase = CeffT + (size_t)r * 128 + half * 64;
    ushort8 breg[8];
    #pragma unroll
    for (int i = 0; i < 8; i++) breg[i] = ((const ushort8*)bbase)[i];

    for (int ct = 0; ct < 8; ct++) {
        __syncthreads();
        #pragma unroll
        for (int i = 0; i < 8; i++) *(ushort8*)&Bs[r][half * 64 + i * 8] = breg[i];
        __syncthreads();
        if (ct < 7) {
            const ushort8* bn = (const ushort8*)(bbase + (size_t)(ct + 1) * 128 * 128);
            #pragma unroll
            for (int i = 0; i < 8; i++) breg[i] = bn[i];
        }
        floatx4 acc[2][8] = {};
        #pragma unroll
        for (int kk = 0; kk < 128; kk += 32) {
            s8v a0 = *(const s8v*)&As[wave * 32 + mn][kk + q * 8];
            s8v a1 = *(const s8v*)&As[wave * 32 + 16 + mn][kk + q * 8];
            #pragma unroll
            for (int j = 0; j < 8; j++) {
                s8v bf = *(const s8v*)&Bs[j * 16 + mn][kk + q * 8];
                acc[0][j] = MFMA16(a0, bf, acc[0][j]);
                acc[1][j] = MFMA16(a1, bf, acc[1][j]);
            }
        }
        float dv[8];
        #pragma unroll
        for (int j = 0; j < 8; j++) dv[j] = Dv[ct * 128 + j * 16 + mn];
        #pragma unroll
        for (int i = 0; i < 2; i++)
            #pragma unroll
            for (int j = 0; j < 8; j++) {
                int col = ct * 128 + j * 16 + mn;
                #pragma unroll
                for (int reg = 0; reg < 4; reg++) {
                    size_t row = row0 + wave * 32 + i * 16 + q * 4 + reg;
                    y[row * 1024 + col] = acc[i][j][reg] + dv[j] * u[row * 1024 + col];
                }
            }
    }
}

// -------------------------------------------------------------- launch ----
extern "C" void kernel_launch(void* const* d_in, const int* in_sizes, int n_in,
                              void* d_out, int out_size, void* d_ws, size_t ws_size,
                              hipStream_t stream) {
    const float* u      = (const float*)d_in[0];
    const float* h_r    = (const float*)d_in[1];
    const float* h_i    = (const float*)d_in[2];
    const float* A_real = (const float*)d_in[3];
    const float* A_imag = (const float*)d_in[4];
    const float* B_real = (const float*)d_in[5];
    const float* B_imag = (const float*)d_in[6];
    const float* C_real = (const float*)d_in[7];
    const float* C_imag = (const float*)d_in[8];
    const float* D      = (const float*)d_in[9];
    const float* inv_dt = (const float*)d_in[10];
    float* out = (float*)d_out;

    // workspace layout (16B aligned)
    float2* P_params = (float2*)d_ws;                     // 256 float2
    float2* P_end    = P_params + 256;                    // NCHUNK*64 float2 (1MB)
    float2* P_carry  = P_end + (size_t)NCHUNK * 64;       // 1MB
    ushort_t* P_W1T  = (ushort_t*)(P_carry + (size_t)NCHUNK * 64);  // 128*1024
    ushort_t* P_Ceff = P_W1T + 128 * 1024;                          // 1024*128
    float* P_Bu      = (float*)(P_Ceff + 1024 * 128);     // M_TOT*128 f32 (33.5MB)
    ushort_t* P_hfix = (ushort_t*)(P_Bu + (size_t)M_TOT * 128);     // M_TOT*128 bf16

    params_kernel<<<1, 64, 0, stream>>>(A_real, A_imag, inv_dt, P_params);
    build_w<<<1024, 256, 0, stream>>>(B_real, B_imag, C_real, C_imag, P_params, P_W1T, P_Ceff);
    gemm1<<<M_TOT / 128, 256, 0, stream>>>(u, P_W1T, P_Bu);
    scan_ends<<<NCHUNK / 4, 256, 0, stream>>>((const float2*)P_Bu, P_params, P_end);
    scan_carry<<<B_SZ, 64, 0, stream>>>(P_end, P_params, h_r, h_i, P_carry);
    scan_final<<<NCHUNK / 4, 256, 0, stream>>>((const float2*)P_Bu, P_params, P_carry,
                                               (unsigned*)P_hfix, out + (size_t)M_TOT * H);
    gemm2<<<M_TOT / 128, 256, 0, stream>>>(P_hfix, P_Ceff, u, D, out);
}